// Round 2
// baseline (16378.448 us; speedup 1.0000x reference)
//
#include <hip/hip_runtime.h>
#include <math.h>

#define Bx 64
#define Tx 800
#define Ux 80
#define INx 3
#define Hx 400
#define Vx 57
#define Kx 10

// Activation layouts (b fastest):
//  out0/out12/out2 : t*25600 + h*64 + b
//  win             : t*3648  + v*64 + b
//  abk             : t*1920  + j*64 + b
//  xT              : t*192   + d*64 + b
//  ohT             : (u*57+v)*64 + b
//
// Persistent recurrence: 256 WGs = 16 u-slices x 16 chain-groups (4 chains).
// __launch_bounds__(448,1): 256-VGPR cap so w[] (168 VGPR for XP15) is truly
// register-resident (v2 had VGPR_Count=112 -> weights streamed from memory).
//
// Cross-WG sync (v3): monotonic per-WG flags (value = completed step count),
// stored by waves 0/1 after their own per-wave vmcnt(0) drain of the sc
// h-stores. No RMW (no serialized atomic chain at LLC), no reset. Every wave
// polls all 32 flags itself (lanes 0..31 -> 2 LLC lines, one wave-load) so
// there is no tid0->syncthreads broadcast hop. h-exchange via single
// global_load_dwordx4 sc0 sc1 per thread (4x fewer LLC requests than v2's
// per-element atomics). Only 2 __syncthreads per step; x-prefetch (waves 2-6)
// overlaps the reduce+signal (waves 0-1). hprev[2] double-buffer decouples
// the reduce's h(t-1) read from the next step's xcat_h overwrite.

typedef float v2f __attribute__((ext_vector_type(2)));
typedef float v4f __attribute__((ext_vector_type(4)));

__device__ __forceinline__ float sigf(float x) { return 1.f / (1.f + expf(-x)); }

__device__ __forceinline__ void pk_lo(v2f& acc, v2f w, v2f h) {
    asm("v_pk_fma_f32 %0, %1, %2, %0 op_sel:[0,0,0] op_sel_hi:[0,1,1]"
        : "+v"(acc) : "v"(w), "v"(h));
}
__device__ __forceinline__ void pk_hi(v2f& acc, v2f w, v2f h) {
    asm("v_pk_fma_f32 %0, %1, %2, %0 op_sel:[1,0,0] op_sel_hi:[1,1,1]"
        : "+v"(acc) : "v"(w), "v"(h));
}

__global__ void k_zero(int* __restrict__ cnt) {
    int i = blockIdx.x * blockDim.x + threadIdx.x;
    if (i < 3 * 16 * 32) cnt[i] = 0;
}

__global__ void k_transpose_x(const float* __restrict__ x, float* __restrict__ xT) {
    int idx = blockIdx.x * blockDim.x + threadIdx.x;
    if (idx >= Tx * INx * Bx) return;
    int b = idx & 63;
    int d = (idx >> 6) % INx;
    int t = idx / (64 * INx);
    xT[idx] = x[((size_t)b * Tx + t) * INx + d];
}

__global__ void k_transpose_oh(const float* __restrict__ oh, float* __restrict__ ohT) {
    int idx = blockIdx.x * blockDim.x + threadIdx.x;
    if (idx >= Ux * Vx * Bx) return;
    int b = idx & 63;
    int uv = idx >> 6;
    int v = uv % Vx;
    int u = uv / Vx;
    ohT[idx] = oh[((size_t)b * Ux + u) * Vx + v];
}

// Wp float2 index: ((us*3*NP) + m)*400 + q ; m = g*NP + p
//  p < 13:  h-pair, kl = 2p,2p+1 (<25 real else 0), col = s*25+kl
//  p >= 13: x-pair, jx = 2(p-13)+e (<29 real), kx = s*29+jx (<xcols real)
__global__ void k_packW(const float* __restrict__ Whh, const float* __restrict__ Wih,
                        float* __restrict__ Wp, int NP, int xcols) {
    int idx = blockIdx.x * blockDim.x + threadIdx.x;
    int total = 16 * 3 * NP * 400;
    if (idx >= total) return;
    int q = idx % 400;
    int m = (idx / 400) % (3 * NP);
    int us = idx / (400 * 3 * NP);
    int g = m / NP, p = m % NP;
    int s = q / 25, u = q % 25;
    int row = g * 400 + us * 25 + u;
    float v0, v1;
    if (p < 13) {
        int kl0 = 2 * p, kl1 = 2 * p + 1;
        v0 = (kl0 < 25) ? Whh[(size_t)row * 400 + s * 25 + kl0] : 0.f;
        v1 = (kl1 < 25) ? Whh[(size_t)row * 400 + s * 25 + kl1] : 0.f;
    } else {
        int jx0 = 2 * (p - 13), jx1 = jx0 + 1;
        int kx0 = s * 29 + jx0, kx1 = s * 29 + jx1;
        v0 = (jx0 < 29 && kx0 < xcols) ? Wih[(size_t)row * xcols + kx0] : 0.f;
        v1 = (jx1 < 29 && kx1 < xcols) ? Wih[(size_t)row * xcols + kx1] : 0.f;
    }
    Wp[(size_t)idx * 2]     = v0;
    Wp[(size_t)idx * 2 + 1] = v1;
}

template <int XP>
__global__ __launch_bounds__(448, 1) void k_rec(
    const float* __restrict__ Wp, const float* __restrict__ prev,
    const float* __restrict__ winb, const float* __restrict__ xT,
    const float* __restrict__ hinit, const float* __restrict__ Wih_small,
    const float* __restrict__ bih, const float* __restrict__ bhh,
    float* __restrict__ outL, int* __restrict__ cnt) {
    constexpr int NP = 13 + XP;
    constexpr int XW = (XP > 0) ? 466 : 4;     // x-plane slots (padded)
    __shared__ __align__(16) float xcat_h[404 * 4];
    __shared__ __align__(16) float xcat_x[2][XW * 4];
    __shared__ __align__(16) float hprev[2][104 * 4];  // own-slice h(t-1), dbuf
    __shared__ v2f red2[8 * 400];              // SoA: [comp][q], conflict-free
    __shared__ float biasLDS[150];
    __shared__ float wih0LDS[225];

    const int tid = threadIdx.x;
    const int us = blockIdx.x >> 4;
    const int cg = blockIdx.x & 15;
    const int cb = cg * 4;
    const int U0 = us * 25;
    const int q = tid;
    const int s = q / 25;
    int* cnt_cg = cnt + cg * 32;

    v2f w[3 * NP];
    if (q < 400) {
        const v2f* Wp2 = (const v2f*)Wp;
        #pragma unroll
        for (int m = 0; m < 3 * NP; ++m)
            w[m] = Wp2[((size_t)(us * 3 * NP) + m) * 400 + q];
    } else {
        #pragma unroll
        for (int m = 0; m < 3 * NP; ++m) w[m] = (v2f){0.f, 0.f};
    }
    if (tid < 75)        biasLDS[tid] = bih[(tid / 25) * 400 + U0 + (tid % 25)];
    else if (tid < 150)  biasLDS[tid] = bhh[((tid - 75) / 25) * 400 + U0 + ((tid - 75) % 25)];
    if (XP == 0 && tid < 225) {
        int u = tid / 9, r9 = tid % 9, g = r9 / 3, d = r9 % 3;
        wih0LDS[tid] = Wih_small[(size_t)(g * 400 + U0 + u) * 3 + d];
    }
    for (int k = tid; k < 404; k += 448)
        *(v4f*)&xcat_h[k * 4] = (v4f){0.f, 0.f, 0.f, 0.f};
    for (int k = tid; k < 2 * XW; k += 448)
        *(v4f*)&xcat_x[0][k * 4] = (v4f){0.f, 0.f, 0.f, 0.f};

    // stage x(0) into plane 0 (ordered by first in-loop __syncthreads)
    if (XP > 0) {
        for (int kx = tid; kx < 460; kx += 448) {
            v4f xv;
            if (kx < 400)      xv = *(const v4f*)(prev + (size_t)kx * 64 + cb);
            else if (kx < 457) xv = *(const v4f*)(winb + (size_t)(kx - 400) * 64 + cb);
            else               xv = *(const v4f*)(xT + (size_t)(kx - 457) * 64 + cb);
            *(v4f*)&xcat_x[0][kx * 4] = xv;
        }
    } else {
        if (tid < 3)
            *(v4f*)&xcat_x[0][tid * 4] = *(const v4f*)(xT + (size_t)tid * 64 + cb);
    }

    for (int t = 0; t < Tx; ++t) {
        const int pl = t & 1;
        // ---- wait for h(t-1) ready, then stage it
        if (t > 0) {
            // all waves poll all 32 flags (lanes 0..31 cover them; 32..63 dup)
            int* fp = cnt_cg + (tid & 31);
            int fv = __hip_atomic_load(fp, __ATOMIC_RELAXED, __HIP_MEMORY_SCOPE_AGENT);
            while (!__all(fv >= t)) {
                __builtin_amdgcn_s_sleep(1);
                fv = __hip_atomic_load(fp, __ATOMIC_RELAXED, __HIP_MEMORY_SCOPE_AGENT);
            }
        }
        if (tid < 400) {
            v4f hv;
            if (t == 0) {
                hv.x = hinit[(size_t)(cb + 0) * 400 + tid];
                hv.y = hinit[(size_t)(cb + 1) * 400 + tid];
                hv.z = hinit[(size_t)(cb + 2) * 400 + tid];
                hv.w = hinit[(size_t)(cb + 3) * 400 + tid];
            } else {
                const float* hp0 = outL + (size_t)(t - 1) * 25600 + (size_t)tid * 64 + cb;
                asm volatile("global_load_dwordx4 %0, %1, off sc0 sc1"
                             : "=v"(hv) : "v"(hp0) : "memory");
                asm volatile("s_waitcnt vmcnt(0)" ::: "memory");
            }
            *(v4f*)&xcat_h[tid * 4] = hv;
            int d = tid - U0;
            if ((unsigned)d < 25u) *(v4f*)&hprev[t & 1][d * 4] = hv;
        }
        __syncthreads();   // S1: xcat_h + x-plane(pl) ready; red2 free

        // ---- dot
        if (q < 400) {
            v2f aR0 = {0, 0}, aR1 = {0, 0}, aZ0 = {0, 0}, aZ1 = {0, 0};
            v2f aHN0 = {0, 0}, aHN1 = {0, 0}, aXN0 = {0, 0}, aXN1 = {0, 0};
            const float* hb = &xcat_h[s * 100];
            #pragma unroll
            for (int p = 0; p < 13; ++p) {
                v2f a01 = *(const v2f*)(hb + 8 * p);
                v2f a23 = *(const v2f*)(hb + 8 * p + 2);
                v2f b01 = *(const v2f*)(hb + 8 * p + 4);
                v2f b23 = *(const v2f*)(hb + 8 * p + 6);
                v2f wr = w[p], wz = w[NP + p], wn = w[2 * NP + p];
                pk_lo(aR0, wr, a01);  pk_lo(aR1, wr, a23);
                pk_hi(aR0, wr, b01);  pk_hi(aR1, wr, b23);
                pk_lo(aZ0, wz, a01);  pk_lo(aZ1, wz, a23);
                pk_hi(aZ0, wz, b01);  pk_hi(aZ1, wz, b23);
                pk_lo(aHN0, wn, a01); pk_lo(aHN1, wn, a23);
                pk_hi(aHN0, wn, b01); pk_hi(aHN1, wn, b23);
            }
            if (XP > 0) {
                const float* xb = &xcat_x[pl][s * 29 * 4];
                #pragma unroll
                for (int p = 0; p < XP; ++p) {
                    v2f a01 = *(const v2f*)(xb + 8 * p);
                    v2f a23 = *(const v2f*)(xb + 8 * p + 2);
                    v2f b01 = *(const v2f*)(xb + 8 * p + 4);
                    v2f b23 = *(const v2f*)(xb + 8 * p + 6);
                    v2f wr = w[13 + p], wz = w[NP + 13 + p], wn = w[2 * NP + 13 + p];
                    pk_lo(aR0, wr, a01);  pk_lo(aR1, wr, a23);
                    pk_hi(aR0, wr, b01);  pk_hi(aR1, wr, b23);
                    pk_lo(aZ0, wz, a01);  pk_lo(aZ1, wz, a23);
                    pk_hi(aZ0, wz, b01);  pk_hi(aZ1, wz, b23);
                    pk_lo(aXN0, wn, a01); pk_lo(aXN1, wn, a23);
                    pk_hi(aXN0, wn, b01); pk_hi(aXN1, wn, b23);
                }
            }
            red2[0 * 400 + q] = aR0;  red2[1 * 400 + q] = aR1;
            red2[2 * 400 + q] = aZ0;  red2[3 * 400 + q] = aZ1;
            red2[4 * 400 + q] = aHN0; red2[5 * 400 + q] = aHN1;
            red2[6 * 400 + q] = aXN0; red2[7 * 400 + q] = aXN1;
        }
        __syncthreads();   // S2: red2 ready; xcat_h free for next step

        // ---- waves 0/1: reduce + activation + sc-store + per-wave signal
        if (tid < 128) {
            if (tid < 100) {
                int u = tid >> 2, c = tid & 3;
                int half = c >> 1, e = c & 1;
                const float* redf = (const float*)red2;
                float R = 0, Z = 0, HN = 0, XN = 0;
                #pragma unroll 4
                for (int s2 = 0; s2 < 16; ++s2) {
                    int idx = s2 * 25 + u;
                    R  += redf[((0 + half) * 400 + idx) * 2 + e];
                    Z  += redf[((2 + half) * 400 + idx) * 2 + e];
                    HN += redf[((4 + half) * 400 + idx) * 2 + e];
                    XN += redf[((6 + half) * 400 + idx) * 2 + e];
                }
                R += biasLDS[u] + biasLDS[75 + u];
                Z += biasLDS[25 + u] + biasLDS[100 + u];
                XN += biasLDS[50 + u];
                HN += biasLDS[125 + u];
                if (XP == 0) {
                    #pragma unroll
                    for (int d = 0; d < 3; ++d) {
                        float xv = xcat_x[pl][d * 4 + c];
                        R  += wih0LDS[u * 9 + 0 + d] * xv;
                        Z  += wih0LDS[u * 9 + 3 + d] * xv;
                        XN += wih0LDS[u * 9 + 6 + d] * xv;
                    }
                }
                float r = sigf(R);
                float z = sigf(Z);
                float n = tanhf(XN + r * HN);
                float hp = hprev[t & 1][u * 4 + c];
                float hnew = (1.f - z) * n + z * hp;
                __hip_atomic_store(outL + (size_t)t * 25600 + (size_t)(U0 + u) * 64 + cb + c,
                                   hnew, __ATOMIC_RELAXED, __HIP_MEMORY_SCOPE_AGENT);
            }
            // per-wave drain of own sc-stores, then monotonic flag = t+1
            asm volatile("s_waitcnt vmcnt(0)" ::: "memory");
            if ((tid & 63) == 0)
                __hip_atomic_store(cnt_cg + us * 2 + (tid >> 6), t + 1,
                                   __ATOMIC_RELAXED, __HIP_MEMORY_SCOPE_AGENT);
        } else if (t + 1 < Tx) {
            // ---- waves 2-6: prefetch x(t+1) into other plane
            const int p2 = (t + 1) & 1;
            if (XP > 0) {
                for (int kx = tid - 128; kx < 460; kx += 320) {
                    v4f xv;
                    if (kx < 400)      xv = *(const v4f*)(prev + (size_t)(t + 1) * 25600 + kx * 64 + cb);
                    else if (kx < 457) xv = *(const v4f*)(winb + (size_t)(t + 1) * 3648 + (kx - 400) * 64 + cb);
                    else               xv = *(const v4f*)(xT + (size_t)(t + 1) * 192 + (kx - 457) * 64 + cb);
                    *(v4f*)&xcat_x[p2][kx * 4] = xv;
                }
            } else {
                if (tid < 131) {
                    int d = tid - 128;
                    *(v4f*)&xcat_x[p2][d * 4] = *(const v4f*)(xT + (size_t)(t + 1) * 192 + d * 64 + cb);
                }
            }
        }
        // no third __syncthreads: next iteration's S1 orders everything.
    }
}

__global__ __launch_bounds__(256) void k_abk(const float* __restrict__ out0,
    const float* __restrict__ Wwin, const float* __restrict__ bwin,
    float* __restrict__ abk) {
    int t = blockIdx.x;
    int b = threadIdx.x & 63;
    int js = threadIdx.x >> 6;
    int j0 = js * 8;
    int nj = min(8, 30 - j0);
    float acc[8];
    for (int i = 0; i < nj; i++) acc[i] = bwin[j0 + i];
    const float* o = out0 + (size_t)t * 25600;
    for (int k = 0; k < Hx; k++) {
        float hv = o[k * 64 + b];
        for (int i = 0; i < nj; i++) acc[i] += Wwin[(j0 + i) * Hx + k] * hv;
    }
    for (int i = 0; i < nj; i++)
        abk[(size_t)t * 1920 + (j0 + i) * 64 + b] = expf(acc[i]);
}

__global__ void k_cumsum(float* __restrict__ abk) {
    int tid = blockIdx.x * blockDim.x + threadIdx.x;
    if (tid >= Kx * Bx) return;
    int b = tid & 63;
    int k = tid >> 6;
    float run = 0.f;
    size_t base = (size_t)(20 + k) * 64 + b;
    for (int t = 0; t < Tx; t++) {
        size_t i = (size_t)t * 1920 + base;
        run += abk[i];
        abk[i] = run;
    }
}

__global__ __launch_bounds__(256) void k_window(const float* __restrict__ abk,
    const float* __restrict__ ohT, float* __restrict__ win) {
    int t = blockIdx.x;
    int b = threadIdx.x & 63;
    int sub = threadIdx.x >> 6;
    __shared__ float phi[Ux][64];

    float al[Kx], be[Kx], kc[Kx];
    const float* ab = abk + (size_t)t * 1920;
    #pragma unroll
    for (int k = 0; k < Kx; k++) {
        al[k] = ab[k * 64 + b];
        be[k] = ab[(10 + k) * 64 + b];
        kc[k] = ab[(20 + k) * 64 + b];
    }
    for (int u = sub * 20; u < sub * 20 + 20; u++) {
        float ssum = 0.f;
        float uf = (float)u;
        #pragma unroll
        for (int k = 0; k < Kx; k++) {
            float d = kc[k] - uf;
            ssum += al[k] * __expf(-be[k] * d * d);
        }
        phi[u][b] = ssum;
    }
    __syncthreads();

    int v0 = sub * 15;
    int nv = min(15, Vx - v0);
    float acc[15];
    for (int i = 0; i < nv; i++) acc[i] = 0.f;
    for (int u = 0; u < Ux; u++) {
        float pv = phi[u][b];
        const float* oh = ohT + (size_t)(u * Vx) * 64;
        for (int i = 0; i < nv; i++) acc[i] += pv * oh[(v0 + i) * 64 + b];
    }
    for (int i = 0; i < nv; i++)
        win[(size_t)t * 3648 + (v0 + i) * 64 + b] = acc[i];
}

__global__ __launch_bounds__(256) void k_mdn(const float* __restrict__ out2,
    const float* __restrict__ Wm, const float* __restrict__ bm,
    float* __restrict__ out) {
    int t = blockIdx.x;
    int b = threadIdx.x & 63;
    int js = threadIdx.x >> 6;
    int j0 = js * 31;
    int nj = min(31, 121 - j0);
    float acc[31];
    for (int i = 0; i < nj; i++) acc[i] = bm[j0 + i];
    const float* o = out2 + (size_t)t * 25600;
    for (int k = 0; k < Hx; k += 4) {
        float i0 = o[k * 64 + b];
        float i1 = o[(k + 1) * 64 + b];
        float i2 = o[(k + 2) * 64 + b];
        float i3 = o[(k + 3) * 64 + b];
        for (int i = 0; i < nj; i++) {
            const float* wp = Wm + (size_t)(j0 + i) * Hx + k;
            float4 qv = *(const float4*)wp;
            acc[i] += qv.x * i0 + qv.y * i1 + qv.z * i2 + qv.w * i3;
        }
    }
    size_t rb = ((size_t)b * Tx + t) * 121;
    for (int i = 0; i < nj; i++) {
        int j = j0 + i;
        float v = acc[i];
        if (j >= 100 && j < 120) v = tanhf(v);
        out[rb + j] = v;
    }
}

extern "C" void kernel_launch(void* const* d_in, const int* in_sizes, int n_in,
                              void* d_out, int out_size, void* d_ws, size_t ws_size,
                              hipStream_t stream) {
    const float* x    = (const float*)d_in[0];
    const float* oneh = (const float*)d_in[1];
    const float* h0i  = (const float*)d_in[2];
    const float* h1i  = (const float*)d_in[3];
    const float* h2i  = (const float*)d_in[4];
    const float* Wih0 = (const float*)d_in[5];
    const float* Whh0 = (const float*)d_in[6];
    const float* bih0 = (const float*)d_in[7];
    const float* bhh0 = (const float*)d_in[8];
    const float* Wih1 = (const float*)d_in[9];
    const float* Whh1 = (const float*)d_in[10];
    const float* bih1 = (const float*)d_in[11];
    const float* bhh1 = (const float*)d_in[12];
    const float* Wwin = (const float*)d_in[13];
    const float* bwin = (const float*)d_in[14];
    const float* Wmdn = (const float*)d_in[15];
    const float* bmdn = (const float*)d_in[16];

    float* ws    = (float*)d_ws;
    float* out0  = ws;                    // 20,480,000
    float* out12 = ws + 20480000;         // 20,480,000
    float* winb  = ws + 40960000;         //  2,918,400
    float* abk   = ws + 43878400;         //  1,536,000
    float* xT    = ws + 45414400;         //    153,600
    float* ohT   = ws + 45568000;         //    291,840
    float* Wp0   = ws + 45859840;         //    499,200
    float* Wp12  = ws + 46359040;         //  1,075,200
    int*   cnt   = (int*)(ws + 47434240); //      1,536 ints

    hipLaunchKernelGGL(k_zero, dim3(6), dim3(256), 0, stream, cnt);
    hipLaunchKernelGGL(k_transpose_x, dim3((Tx * INx * Bx + 255) / 256), dim3(256), 0, stream, x, xT);
    hipLaunchKernelGGL(k_transpose_oh, dim3((Ux * Vx * Bx + 255) / 256), dim3(256), 0, stream, oneh, ohT);
    hipLaunchKernelGGL(k_packW, dim3((16 * 3 * 13 * 400 + 255) / 256), dim3(256), 0, stream,
                       Whh0, Wih0, Wp0, 13, 3);
    hipLaunchKernelGGL(k_packW, dim3((16 * 3 * 28 * 400 + 255) / 256), dim3(256), 0, stream,
                       Whh1, Wih1, Wp12, 28, 460);

    hipLaunchKernelGGL((k_rec<0>), dim3(256), dim3(448), 0, stream,
                       Wp0, (const float*)nullptr, (const float*)nullptr, xT,
                       h0i, Wih0, bih0, bhh0, out0, cnt + 0 * 512);

    hipLaunchKernelGGL(k_abk, dim3(Tx), dim3(256), 0, stream, out0, Wwin, bwin, abk);
    hipLaunchKernelGGL(k_cumsum, dim3(10), dim3(64), 0, stream, abk);
    hipLaunchKernelGGL(k_window, dim3(Tx), dim3(256), 0, stream, abk, ohT, winb);

    hipLaunchKernelGGL((k_rec<15>), dim3(256), dim3(448), 0, stream,
                       Wp12, out0, winb, xT, h1i, (const float*)nullptr,
                       bih1, bhh1, out12, cnt + 1 * 512);
    hipLaunchKernelGGL((k_rec<15>), dim3(256), dim3(448), 0, stream,
                       Wp12, out12, winb, xT, h2i, (const float*)nullptr,
                       bih1, bhh1, out0, cnt + 2 * 512);

    hipLaunchKernelGGL(k_mdn, dim3(Tx), dim3(256), 0, stream, out0, Wmdn, bmdn, (float*)d_out);
}

// Round 3
// 13778.769 us; speedup vs baseline: 1.1887x; 1.1887x over previous
//
#include <hip/hip_runtime.h>
#include <math.h>

#define Bx 64
#define Tx 800
#define Ux 80
#define INx 3
#define Hx 400
#define Vx 57
#define Kx 10

// Activation layouts (b fastest):
//  out0/out12/out2 : t*25600 + h*64 + b
//  win             : t*3648  + v*64 + b
//  abk             : t*1920  + j*64 + b
//  xT              : t*192   + d*64 + b
//  ohT             : (u*57+v)*64 + b
//
// Persistent recurrence: 256 WGs = 16 u-slices x 16 chain-groups (4 chains).
//
// Cross-WG sync (v4):
//  - producer: wave 0 does the whole reduce (100 outputs, 2/lane), sc-stores
//    h(t), drains vmcnt once, stores ONE monotonic flag (value t+1) per WG.
//    16 flags per cg = one 64B line, no RMW chain (v2's serialization), no
//    2-line 32-producer spread (v3).
//  - consumer: ONLY wave 0 polls the 16 flags (lane&15), then __syncthreads
//    releases the block. v3's all-wave polling (1792 polling waves) flooded
//    the LLC and slowed the producers' critical stores -> 28% regression.
//  - h-exchange: one global_load_dwordx4 sc0 sc1 per thread.
//  - waves 1-6 prefetch x(t+1) into the other LDS plane while wave 0
//    reduces/signals (no third barrier; next poll-release sync orders it).
//  - weights: split into wr/wz/wn[NP] to coax register promotion
//    (v2/v3 VGPR_Count=112/116 proves w[] was NOT register-resident).

typedef float v2f __attribute__((ext_vector_type(2)));
typedef float v4f __attribute__((ext_vector_type(4)));

__device__ __forceinline__ float sigf(float x) { return 1.f / (1.f + expf(-x)); }

__device__ __forceinline__ void pk_lo(v2f& acc, v2f w, v2f h) {
    asm("v_pk_fma_f32 %0, %1, %2, %0 op_sel:[0,0,0] op_sel_hi:[0,1,1]"
        : "+v"(acc) : "v"(w), "v"(h));
}
__device__ __forceinline__ void pk_hi(v2f& acc, v2f w, v2f h) {
    asm("v_pk_fma_f32 %0, %1, %2, %0 op_sel:[1,0,0] op_sel_hi:[1,1,1]"
        : "+v"(acc) : "v"(w), "v"(h));
}

__global__ void k_zero(int* __restrict__ cnt) {
    int i = blockIdx.x * blockDim.x + threadIdx.x;
    if (i < 3 * 16 * 32) cnt[i] = 0;
}

__global__ void k_transpose_x(const float* __restrict__ x, float* __restrict__ xT) {
    int idx = blockIdx.x * blockDim.x + threadIdx.x;
    if (idx >= Tx * INx * Bx) return;
    int b = idx & 63;
    int d = (idx >> 6) % INx;
    int t = idx / (64 * INx);
    xT[idx] = x[((size_t)b * Tx + t) * INx + d];
}

__global__ void k_transpose_oh(const float* __restrict__ oh, float* __restrict__ ohT) {
    int idx = blockIdx.x * blockDim.x + threadIdx.x;
    if (idx >= Ux * Vx * Bx) return;
    int b = idx & 63;
    int uv = idx >> 6;
    int v = uv % Vx;
    int u = uv / Vx;
    ohT[idx] = oh[((size_t)b * Ux + u) * Vx + v];
}

// Wp float2 index: ((us*3*NP) + m)*400 + q ; m = g*NP + p
//  p < 13:  h-pair, kl = 2p,2p+1 (<25 real else 0), col = s*25+kl
//  p >= 13: x-pair, jx = 2(p-13)+e (<29 real), kx = s*29+jx (<xcols real)
__global__ void k_packW(const float* __restrict__ Whh, const float* __restrict__ Wih,
                        float* __restrict__ Wp, int NP, int xcols) {
    int idx = blockIdx.x * blockDim.x + threadIdx.x;
    int total = 16 * 3 * NP * 400;
    if (idx >= total) return;
    int q = idx % 400;
    int m = (idx / 400) % (3 * NP);
    int us = idx / (400 * 3 * NP);
    int g = m / NP, p = m % NP;
    int s = q / 25, u = q % 25;
    int row = g * 400 + us * 25 + u;
    float v0, v1;
    if (p < 13) {
        int kl0 = 2 * p, kl1 = 2 * p + 1;
        v0 = (kl0 < 25) ? Whh[(size_t)row * 400 + s * 25 + kl0] : 0.f;
        v1 = (kl1 < 25) ? Whh[(size_t)row * 400 + s * 25 + kl1] : 0.f;
    } else {
        int jx0 = 2 * (p - 13), jx1 = jx0 + 1;
        int kx0 = s * 29 + jx0, kx1 = s * 29 + jx1;
        v0 = (jx0 < 29 && kx0 < xcols) ? Wih[(size_t)row * xcols + kx0] : 0.f;
        v1 = (jx1 < 29 && kx1 < xcols) ? Wih[(size_t)row * xcols + kx1] : 0.f;
    }
    Wp[(size_t)idx * 2]     = v0;
    Wp[(size_t)idx * 2 + 1] = v1;
}

template <int XP>
__global__ __launch_bounds__(448, 1) void k_rec(
    const float* __restrict__ Wp, const float* __restrict__ prev,
    const float* __restrict__ winb, const float* __restrict__ xT,
    const float* __restrict__ hinit, const float* __restrict__ Wih_small,
    const float* __restrict__ bih, const float* __restrict__ bhh,
    float* __restrict__ outL, int* __restrict__ cnt) {
    constexpr int NP = 13 + XP;
    constexpr int XW = (XP > 0) ? 466 : 4;     // x-plane slots (padded)
    __shared__ __align__(16) float xcat_h[404 * 4];
    __shared__ __align__(16) float xcat_x[2][XW * 4];
    __shared__ __align__(16) float hprev[2][104 * 4];  // own-slice h(t-1), dbuf
    __shared__ v2f red2[8 * 400];              // SoA: [comp][q], conflict-free
    __shared__ float biasLDS[150];
    __shared__ float wih0LDS[225];

    const int tid = threadIdx.x;
    const int us = blockIdx.x >> 4;
    const int cg = blockIdx.x & 15;
    const int cb = cg * 4;
    const int U0 = us * 25;
    const int q = tid;
    const int s = q / 25;
    int* cnt_cg = cnt + cg * 32;   // flags [0..15], one 64B line

    v2f wr[NP], wz[NP], wn[NP];
    if (q < 400) {
        const v2f* Wp2 = (const v2f*)Wp;
        const size_t base = (size_t)(us * 3 * NP) * 400 + q;
        #pragma unroll
        for (int m = 0; m < NP; ++m) {
            wr[m] = Wp2[base + (size_t)m * 400];
            wz[m] = Wp2[base + (size_t)(NP + m) * 400];
            wn[m] = Wp2[base + (size_t)(2 * NP + m) * 400];
        }
    } else {
        #pragma unroll
        for (int m = 0; m < NP; ++m) {
            wr[m] = (v2f){0.f, 0.f}; wz[m] = (v2f){0.f, 0.f}; wn[m] = (v2f){0.f, 0.f};
        }
    }
    if (tid < 75)        biasLDS[tid] = bih[(tid / 25) * 400 + U0 + (tid % 25)];
    else if (tid < 150)  biasLDS[tid] = bhh[((tid - 75) / 25) * 400 + U0 + ((tid - 75) % 25)];
    if (XP == 0 && tid < 225) {
        int u = tid / 9, r9 = tid % 9, g = r9 / 3, d = r9 % 3;
        wih0LDS[tid] = Wih_small[(size_t)(g * 400 + U0 + u) * 3 + d];
    }
    for (int k = tid; k < 404; k += 448)
        *(v4f*)&xcat_h[k * 4] = (v4f){0.f, 0.f, 0.f, 0.f};
    for (int k = tid; k < 2 * XW; k += 448)
        *(v4f*)&xcat_x[0][k * 4] = (v4f){0.f, 0.f, 0.f, 0.f};

    // stage x(0) into plane 0 (ordered by S1 of t=0)
    if (XP > 0) {
        for (int kx = tid; kx < 460; kx += 448) {
            v4f xv;
            if (kx < 400)      xv = *(const v4f*)(prev + (size_t)kx * 64 + cb);
            else if (kx < 457) xv = *(const v4f*)(winb + (size_t)(kx - 400) * 64 + cb);
            else               xv = *(const v4f*)(xT + (size_t)(kx - 457) * 64 + cb);
            *(v4f*)&xcat_x[0][kx * 4] = xv;
        }
    } else {
        if (tid < 3)
            *(v4f*)&xcat_x[0][tid * 4] = *(const v4f*)(xT + (size_t)tid * 64 + cb);
    }

    for (int t = 0; t < Tx; ++t) {
        const int pl = t & 1;
        // ---- wait for h(t-1): wave 0 polls the single flag line, then release
        if (t > 0) {
            if (tid < 64) {
                int* fp = cnt_cg + (tid & 15);
                int fv = __hip_atomic_load(fp, __ATOMIC_RELAXED, __HIP_MEMORY_SCOPE_AGENT);
                while (!__all(fv >= t)) {
                    __builtin_amdgcn_s_sleep(1);
                    fv = __hip_atomic_load(fp, __ATOMIC_RELAXED, __HIP_MEMORY_SCOPE_AGENT);
                }
            }
            __syncthreads();   // release: h(t-1) globally visible
        }
        // ---- stage h(t-1)
        if (tid < 400) {
            v4f hv;
            if (t == 0) {
                hv.x = hinit[(size_t)(cb + 0) * 400 + tid];
                hv.y = hinit[(size_t)(cb + 1) * 400 + tid];
                hv.z = hinit[(size_t)(cb + 2) * 400 + tid];
                hv.w = hinit[(size_t)(cb + 3) * 400 + tid];
            } else {
                const float* hp0 = outL + (size_t)(t - 1) * 25600 + (size_t)tid * 64 + cb;
                asm volatile("global_load_dwordx4 %0, %1, off sc0 sc1"
                             : "=v"(hv) : "v"(hp0) : "memory");
                asm volatile("s_waitcnt vmcnt(0)" ::: "memory");
            }
            *(v4f*)&xcat_h[tid * 4] = hv;
            int d = tid - U0;
            if ((unsigned)d < 25u) *(v4f*)&hprev[t & 1][d * 4] = hv;
        }
        __syncthreads();   // S1: xcat_h + x-plane(pl) ready; red2 free

        // ---- dot
        if (q < 400) {
            v2f aR0 = {0, 0}, aR1 = {0, 0}, aZ0 = {0, 0}, aZ1 = {0, 0};
            v2f aHN0 = {0, 0}, aHN1 = {0, 0}, aXN0 = {0, 0}, aXN1 = {0, 0};
            const float* hb = &xcat_h[s * 100];
            #pragma unroll
            for (int p = 0; p < 13; ++p) {
                v2f a01 = *(const v2f*)(hb + 8 * p);
                v2f a23 = *(const v2f*)(hb + 8 * p + 2);
                v2f b01 = *(const v2f*)(hb + 8 * p + 4);
                v2f b23 = *(const v2f*)(hb + 8 * p + 6);
                v2f r_ = wr[p], z_ = wz[p], n_ = wn[p];
                pk_lo(aR0, r_, a01);  pk_lo(aR1, r_, a23);
                pk_hi(aR0, r_, b01);  pk_hi(aR1, r_, b23);
                pk_lo(aZ0, z_, a01);  pk_lo(aZ1, z_, a23);
                pk_hi(aZ0, z_, b01);  pk_hi(aZ1, z_, b23);
                pk_lo(aHN0, n_, a01); pk_lo(aHN1, n_, a23);
                pk_hi(aHN0, n_, b01); pk_hi(aHN1, n_, b23);
            }
            if (XP > 0) {
                const float* xb = &xcat_x[pl][s * 29 * 4];
                #pragma unroll
                for (int p = 0; p < XP; ++p) {
                    v2f a01 = *(const v2f*)(xb + 8 * p);
                    v2f a23 = *(const v2f*)(xb + 8 * p + 2);
                    v2f b01 = *(const v2f*)(xb + 8 * p + 4);
                    v2f b23 = *(const v2f*)(xb + 8 * p + 6);
                    v2f r_ = wr[13 + p], z_ = wz[13 + p], n_ = wn[13 + p];
                    pk_lo(aR0, r_, a01);  pk_lo(aR1, r_, a23);
                    pk_hi(aR0, r_, b01);  pk_hi(aR1, r_, b23);
                    pk_lo(aZ0, z_, a01);  pk_lo(aZ1, z_, a23);
                    pk_hi(aZ0, z_, b01);  pk_hi(aZ1, z_, b23);
                    pk_lo(aXN0, n_, a01); pk_lo(aXN1, n_, a23);
                    pk_hi(aXN0, n_, b01); pk_hi(aXN1, n_, b23);
                }
            }
            red2[0 * 400 + q] = aR0;  red2[1 * 400 + q] = aR1;
            red2[2 * 400 + q] = aZ0;  red2[3 * 400 + q] = aZ1;
            red2[4 * 400 + q] = aHN0; red2[5 * 400 + q] = aHN1;
            red2[6 * 400 + q] = aXN0; red2[7 * 400 + q] = aXN1;
        }
        __syncthreads();   // S2: red2 ready; xcat_h free for next step

        // ---- wave 0: reduce (2 outputs/lane) + activation + sc-store + signal
        if (tid < 64) {
            #pragma unroll
            for (int rep = 0; rep < 2; ++rep) {
                int o = tid + rep * 64;
                if (o < 100) {
                    int u = o >> 2, c = o & 3;
                    int half = c >> 1, e = c & 1;
                    const float* redf = (const float*)red2;
                    float R = 0, Z = 0, HN = 0, XN = 0;
                    #pragma unroll 4
                    for (int s2 = 0; s2 < 16; ++s2) {
                        int idx = s2 * 25 + u;
                        R  += redf[((0 + half) * 400 + idx) * 2 + e];
                        Z  += redf[((2 + half) * 400 + idx) * 2 + e];
                        HN += redf[((4 + half) * 400 + idx) * 2 + e];
                        XN += redf[((6 + half) * 400 + idx) * 2 + e];
                    }
                    R += biasLDS[u] + biasLDS[75 + u];
                    Z += biasLDS[25 + u] + biasLDS[100 + u];
                    XN += biasLDS[50 + u];
                    HN += biasLDS[125 + u];
                    if (XP == 0) {
                        #pragma unroll
                        for (int d = 0; d < 3; ++d) {
                            float xv = xcat_x[pl][d * 4 + c];
                            R  += wih0LDS[u * 9 + 0 + d] * xv;
                            Z  += wih0LDS[u * 9 + 3 + d] * xv;
                            XN += wih0LDS[u * 9 + 6 + d] * xv;
                        }
                    }
                    float r = sigf(R);
                    float z = sigf(Z);
                    float n = tanhf(XN + r * HN);
                    float hp = hprev[t & 1][u * 4 + c];
                    float hnew = (1.f - z) * n + z * hp;
                    __hip_atomic_store(outL + (size_t)t * 25600 + (size_t)(U0 + u) * 64 + cb + c,
                                       hnew, __ATOMIC_RELAXED, __HIP_MEMORY_SCOPE_AGENT);
                }
            }
            // single drain of this wave's sc-stores, then monotonic flag = t+1
            asm volatile("s_waitcnt vmcnt(0)" ::: "memory");
            if (tid == 0)
                __hip_atomic_store(cnt_cg + us, t + 1,
                                   __ATOMIC_RELAXED, __HIP_MEMORY_SCOPE_AGENT);
        } else if (t + 1 < Tx) {
            // ---- waves 1-6: prefetch x(t+1) into other plane
            const int p2 = (t + 1) & 1;
            if (XP > 0) {
                for (int kx = tid - 64; kx < 460; kx += 384) {
                    v4f xv;
                    if (kx < 400)      xv = *(const v4f*)(prev + (size_t)(t + 1) * 25600 + kx * 64 + cb);
                    else if (kx < 457) xv = *(const v4f*)(winb + (size_t)(t + 1) * 3648 + (kx - 400) * 64 + cb);
                    else               xv = *(const v4f*)(xT + (size_t)(t + 1) * 192 + (kx - 457) * 64 + cb);
                    *(v4f*)&xcat_x[p2][kx * 4] = xv;
                }
            } else {
                if (tid < 67) {
                    int d = tid - 64;
                    *(v4f*)&xcat_x[p2][d * 4] = *(const v4f*)(xT + (size_t)(t + 1) * 192 + d * 64 + cb);
                }
            }
        }
        // no third __syncthreads: next step's poll-release sync orders LDS.
    }
}

__global__ __launch_bounds__(256) void k_abk(const float* __restrict__ out0,
    const float* __restrict__ Wwin, const float* __restrict__ bwin,
    float* __restrict__ abk) {
    int t = blockIdx.x;
    int b = threadIdx.x & 63;
    int js = threadIdx.x >> 6;
    int j0 = js * 8;
    int nj = min(8, 30 - j0);
    float acc[8];
    for (int i = 0; i < nj; i++) acc[i] = bwin[j0 + i];
    const float* o = out0 + (size_t)t * 25600;
    for (int k = 0; k < Hx; k++) {
        float hv = o[k * 64 + b];
        for (int i = 0; i < nj; i++) acc[i] += Wwin[(j0 + i) * Hx + k] * hv;
    }
    for (int i = 0; i < nj; i++)
        abk[(size_t)t * 1920 + (j0 + i) * 64 + b] = expf(acc[i]);
}

__global__ void k_cumsum(float* __restrict__ abk) {
    int tid = blockIdx.x * blockDim.x + threadIdx.x;
    if (tid >= Kx * Bx) return;
    int b = tid & 63;
    int k = tid >> 6;
    float run = 0.f;
    size_t base = (size_t)(20 + k) * 64 + b;
    for (int t = 0; t < Tx; t++) {
        size_t i = (size_t)t * 1920 + base;
        run += abk[i];
        abk[i] = run;
    }
}

__global__ __launch_bounds__(256) void k_window(const float* __restrict__ abk,
    const float* __restrict__ ohT, float* __restrict__ win) {
    int t = blockIdx.x;
    int b = threadIdx.x & 63;
    int sub = threadIdx.x >> 6;
    __shared__ float phi[Ux][64];

    float al[Kx], be[Kx], kc[Kx];
    const float* ab = abk + (size_t)t * 1920;
    #pragma unroll
    for (int k = 0; k < Kx; k++) {
        al[k] = ab[k * 64 + b];
        be[k] = ab[(10 + k) * 64 + b];
        kc[k] = ab[(20 + k) * 64 + b];
    }
    for (int u = sub * 20; u < sub * 20 + 20; u++) {
        float ssum = 0.f;
        float uf = (float)u;
        #pragma unroll
        for (int k = 0; k < Kx; k++) {
            float d = kc[k] - uf;
            ssum += al[k] * __expf(-be[k] * d * d);
        }
        phi[u][b] = ssum;
    }
    __syncthreads();

    int v0 = sub * 15;
    int nv = min(15, Vx - v0);
    float acc[15];
    for (int i = 0; i < nv; i++) acc[i] = 0.f;
    for (int u = 0; u < Ux; u++) {
        float pv = phi[u][b];
        const float* oh = ohT + (size_t)(u * Vx) * 64;
        for (int i = 0; i < nv; i++) acc[i] += pv * oh[(v0 + i) * 64 + b];
    }
    for (int i = 0; i < nv; i++)
        win[(size_t)t * 3648 + (v0 + i) * 64 + b] = acc[i];
}

__global__ __launch_bounds__(256) void k_mdn(const float* __restrict__ out2,
    const float* __restrict__ Wm, const float* __restrict__ bm,
    float* __restrict__ out) {
    int t = blockIdx.x;
    int b = threadIdx.x & 63;
    int js = threadIdx.x >> 6;
    int j0 = js * 31;
    int nj = min(31, 121 - j0);
    float acc[31];
    for (int i = 0; i < nj; i++) acc[i] = bm[j0 + i];
    const float* o = out2 + (size_t)t * 25600;
    for (int k = 0; k < Hx; k += 4) {
        float i0 = o[k * 64 + b];
        float i1 = o[(k + 1) * 64 + b];
        float i2 = o[(k + 2) * 64 + b];
        float i3 = o[(k + 3) * 64 + b];
        for (int i = 0; i < nj; i++) {
            const float* wp = Wm + (size_t)(j0 + i) * Hx + k;
            float4 qv = *(const float4*)wp;
            acc[i] += qv.x * i0 + qv.y * i1 + qv.z * i2 + qv.w * i3;
        }
    }
    size_t rb = ((size_t)b * Tx + t) * 121;
    for (int i = 0; i < nj; i++) {
        int j = j0 + i;
        float v = acc[i];
        if (j >= 100 && j < 120) v = tanhf(v);
        out[rb + j] = v;
    }
}

extern "C" void kernel_launch(void* const* d_in, const int* in_sizes, int n_in,
                              void* d_out, int out_size, void* d_ws, size_t ws_size,
                              hipStream_t stream) {
    const float* x    = (const float*)d_in[0];
    const float* oneh = (const float*)d_in[1];
    const float* h0i  = (const float*)d_in[2];
    const float* h1i  = (const float*)d_in[3];
    const float* h2i  = (const float*)d_in[4];
    const float* Wih0 = (const float*)d_in[5];
    const float* Whh0 = (const float*)d_in[6];
    const float* bih0 = (const float*)d_in[7];
    const float* bhh0 = (const float*)d_in[8];
    const float* Wih1 = (const float*)d_in[9];
    const float* Whh1 = (const float*)d_in[10];
    const float* bih1 = (const float*)d_in[11];
    const float* bhh1 = (const float*)d_in[12];
    const float* Wwin = (const float*)d_in[13];
    const float* bwin = (const float*)d_in[14];
    const float* Wmdn = (const float*)d_in[15];
    const float* bmdn = (const float*)d_in[16];

    float* ws    = (float*)d_ws;
    float* out0  = ws;                    // 20,480,000
    float* out12 = ws + 20480000;         // 20,480,000
    float* winb  = ws + 40960000;         //  2,918,400
    float* abk   = ws + 43878400;         //  1,536,000
    float* xT    = ws + 45414400;         //    153,600
    float* ohT   = ws + 45568000;         //    291,840
    float* Wp0   = ws + 45859840;         //    499,200
    float* Wp12  = ws + 46359040;         //  1,075,200
    int*   cnt   = (int*)(ws + 47434240); //      1,536 ints

    hipLaunchKernelGGL(k_zero, dim3(6), dim3(256), 0, stream, cnt);
    hipLaunchKernelGGL(k_transpose_x, dim3((Tx * INx * Bx + 255) / 256), dim3(256), 0, stream, x, xT);
    hipLaunchKernelGGL(k_transpose_oh, dim3((Ux * Vx * Bx + 255) / 256), dim3(256), 0, stream, oneh, ohT);
    hipLaunchKernelGGL(k_packW, dim3((16 * 3 * 13 * 400 + 255) / 256), dim3(256), 0, stream,
                       Whh0, Wih0, Wp0, 13, 3);
    hipLaunchKernelGGL(k_packW, dim3((16 * 3 * 28 * 400 + 255) / 256), dim3(256), 0, stream,
                       Whh1, Wih1, Wp12, 28, 460);

    hipLaunchKernelGGL((k_rec<0>), dim3(256), dim3(448), 0, stream,
                       Wp0, (const float*)nullptr, (const float*)nullptr, xT,
                       h0i, Wih0, bih0, bhh0, out0, cnt + 0 * 512);

    hipLaunchKernelGGL(k_abk, dim3(Tx), dim3(256), 0, stream, out0, Wwin, bwin, abk);
    hipLaunchKernelGGL(k_cumsum, dim3(10), dim3(64), 0, stream, abk);
    hipLaunchKernelGGL(k_window, dim3(Tx), dim3(256), 0, stream, abk, ohT, winb);

    hipLaunchKernelGGL((k_rec<15>), dim3(256), dim3(448), 0, stream,
                       Wp12, out0, winb, xT, h1i, (const float*)nullptr,
                       bih1, bhh1, out12, cnt + 1 * 512);
    hipLaunchKernelGGL((k_rec<15>), dim3(256), dim3(448), 0, stream,
                       Wp12, out12, winb, xT, h2i, (const float*)nullptr,
                       bih1, bhh1, out0, cnt + 2 * 512);

    hipLaunchKernelGGL(k_mdn, dim3(Tx), dim3(256), 0, stream, out0, Wmdn, bmdn, (float*)d_out);
}

// Round 4
// 13390.559 us; speedup vs baseline: 1.2231x; 1.0290x over previous
//
#include <hip/hip_runtime.h>
#include <math.h>

#define Bx 64
#define Tx 800
#define Ux 80
#define INx 3
#define Hx 400
#define Vx 57
#define Kx 10

// Activation layouts (b fastest):
//  out0/out12/out2 : t*25600 + h*64 + b
//  win             : t*3648  + v*64 + b
//  abk             : t*1920  + j*64 + b
//  xT              : t*192   + d*64 + b
//  ohT             : (u*57+v)*64 + b
//
// Persistent recurrence: 256 WGs = 16 u-slices x 16 chain-groups (4 chains).
// v5 mapping: us = blk&15, cg = blk>>4  -> XCD (blk%8) hosts 2 u-slices
// (538KB weights, L2-resident) x all 16 cgs. (v4 mapping put all 16 slices
// = 4.3MB on each XCD -> L2 thrash.)
//
// v5 weight pinning: after the preamble load, an empty inline-asm with
// "+v" on every weight register redefines the values, so the compiler can
// no longer sink/remat the weight loads inside the t-loop (v2-v4 all had
// VGPR_Count ~112-120 -> 268.8KB/WG/step streamed through L1; ~1.75us/step
// of pure L1 BW + address VALU). Budget: 168 (XP15 weights) + ~50 working
// < 256 cap (448 thr -> 2 waves/SIMD).
//
// Cross-WG sync (unchanged from v4):
//  - producer: wave 0 reduces all 100 outputs, sc-stores h(t), one vmcnt
//    drain, ONE monotonic flag (t+1) per WG; 16 flags/cg = one 64B line.
//  - consumer: wave 0 polls the flag line, __syncthreads releases.
//  - h-exchange: one global_load_dwordx4 sc0 sc1 per thread.
//  - waves 1-6 prefetch x(t+1) into the other LDS plane meanwhile.

typedef float v2f __attribute__((ext_vector_type(2)));
typedef float v4f __attribute__((ext_vector_type(4)));

__device__ __forceinline__ float sigf(float x) { return 1.f / (1.f + expf(-x)); }

__device__ __forceinline__ void pk_lo(v2f& acc, v2f w, v2f h) {
    asm("v_pk_fma_f32 %0, %1, %2, %0 op_sel:[0,0,0] op_sel_hi:[0,1,1]"
        : "+v"(acc) : "v"(w), "v"(h));
}
__device__ __forceinline__ void pk_hi(v2f& acc, v2f w, v2f h) {
    asm("v_pk_fma_f32 %0, %1, %2, %0 op_sel:[1,0,0] op_sel_hi:[1,1,1]"
        : "+v"(acc) : "v"(w), "v"(h));
}

__global__ void k_zero(int* __restrict__ cnt) {
    int i = blockIdx.x * blockDim.x + threadIdx.x;
    if (i < 3 * 16 * 32) cnt[i] = 0;
}

__global__ void k_transpose_x(const float* __restrict__ x, float* __restrict__ xT) {
    int idx = blockIdx.x * blockDim.x + threadIdx.x;
    if (idx >= Tx * INx * Bx) return;
    int b = idx & 63;
    int d = (idx >> 6) % INx;
    int t = idx / (64 * INx);
    xT[idx] = x[((size_t)b * Tx + t) * INx + d];
}

__global__ void k_transpose_oh(const float* __restrict__ oh, float* __restrict__ ohT) {
    int idx = blockIdx.x * blockDim.x + threadIdx.x;
    if (idx >= Ux * Vx * Bx) return;
    int b = idx & 63;
    int uv = idx >> 6;
    int v = uv % Vx;
    int u = uv / Vx;
    ohT[idx] = oh[((size_t)b * Ux + u) * Vx + v];
}

// Wp float2 index: ((us*3*NP) + m)*400 + q ; m = g*NP + p
//  p < 13:  h-pair, kl = 2p,2p+1 (<25 real else 0), col = s*25+kl
//  p >= 13: x-pair, jx = 2(p-13)+e (<29 real), kx = s*29+jx (<xcols real)
__global__ void k_packW(const float* __restrict__ Whh, const float* __restrict__ Wih,
                        float* __restrict__ Wp, int NP, int xcols) {
    int idx = blockIdx.x * blockDim.x + threadIdx.x;
    int total = 16 * 3 * NP * 400;
    if (idx >= total) return;
    int q = idx % 400;
    int m = (idx / 400) % (3 * NP);
    int us = idx / (400 * 3 * NP);
    int g = m / NP, p = m % NP;
    int s = q / 25, u = q % 25;
    int row = g * 400 + us * 25 + u;
    float v0, v1;
    if (p < 13) {
        int kl0 = 2 * p, kl1 = 2 * p + 1;
        v0 = (kl0 < 25) ? Whh[(size_t)row * 400 + s * 25 + kl0] : 0.f;
        v1 = (kl1 < 25) ? Whh[(size_t)row * 400 + s * 25 + kl1] : 0.f;
    } else {
        int jx0 = 2 * (p - 13), jx1 = jx0 + 1;
        int kx0 = s * 29 + jx0, kx1 = s * 29 + jx1;
        v0 = (jx0 < 29 && kx0 < xcols) ? Wih[(size_t)row * xcols + kx0] : 0.f;
        v1 = (jx1 < 29 && kx1 < xcols) ? Wih[(size_t)row * xcols + kx1] : 0.f;
    }
    Wp[(size_t)idx * 2]     = v0;
    Wp[(size_t)idx * 2 + 1] = v1;
}

template <int XP>
__global__ __launch_bounds__(448, 1) void k_rec(
    const float* __restrict__ Wp, const float* __restrict__ prev,
    const float* __restrict__ winb, const float* __restrict__ xT,
    const float* __restrict__ hinit, const float* __restrict__ Wih_small,
    const float* __restrict__ bih, const float* __restrict__ bhh,
    float* __restrict__ outL, int* __restrict__ cnt) {
    constexpr int NP = 13 + XP;
    constexpr int XW = (XP > 0) ? 466 : 4;     // x-plane slots (padded)
    __shared__ __align__(16) float xcat_h[404 * 4];
    __shared__ __align__(16) float xcat_x[2][XW * 4];
    __shared__ __align__(16) float hprev[2][104 * 4];  // own-slice h(t-1), dbuf
    __shared__ v2f red2[8 * 400];              // SoA: [comp][q], conflict-free
    __shared__ float biasLDS[150];
    __shared__ float wih0LDS[225];

    const int tid = threadIdx.x;
    const int us = blockIdx.x & 15;            // v5: u-slice on XCD (blk%8)
    const int cg = blockIdx.x >> 4;            // v5: chain-group spans XCDs
    const int cb = cg * 4;
    const int U0 = us * 25;
    const int q = tid;
    const int s = q / 25;
    int* cnt_cg = cnt + cg * 32;   // flags [0..15], one 64B line

    v2f wr[NP], wz[NP], wn[NP];
    if (q < 400) {
        const v2f* Wp2 = (const v2f*)Wp;
        const size_t base = (size_t)(us * 3 * NP) * 400 + q;
        #pragma unroll
        for (int m = 0; m < NP; ++m) {
            wr[m] = Wp2[base + (size_t)m * 400];
            wz[m] = Wp2[base + (size_t)(NP + m) * 400];
            wn[m] = Wp2[base + (size_t)(2 * NP + m) * 400];
        }
    } else {
        #pragma unroll
        for (int m = 0; m < NP; ++m) {
            wr[m] = (v2f){0.f, 0.f}; wz[m] = (v2f){0.f, 0.f}; wn[m] = (v2f){0.f, 0.f};
        }
    }
    // Pin the weights in VGPRs: the asm redefines each value, so the loads
    // above cannot be sunk/rematerialized inside the t-loop.
    #pragma unroll
    for (int m = 0; m < NP; ++m) {
        asm volatile("" : "+v"(wr[m]));
        asm volatile("" : "+v"(wz[m]));
        asm volatile("" : "+v"(wn[m]));
    }
    if (tid < 75)        biasLDS[tid] = bih[(tid / 25) * 400 + U0 + (tid % 25)];
    else if (tid < 150)  biasLDS[tid] = bhh[((tid - 75) / 25) * 400 + U0 + ((tid - 75) % 25)];
    if (XP == 0 && tid < 225) {
        int u = tid / 9, r9 = tid % 9, g = r9 / 3, d = r9 % 3;
        wih0LDS[tid] = Wih_small[(size_t)(g * 400 + U0 + u) * 3 + d];
    }
    for (int k = tid; k < 404; k += 448)
        *(v4f*)&xcat_h[k * 4] = (v4f){0.f, 0.f, 0.f, 0.f};
    for (int k = tid; k < 2 * XW; k += 448)
        *(v4f*)&xcat_x[0][k * 4] = (v4f){0.f, 0.f, 0.f, 0.f};

    // stage x(0) into plane 0 (ordered by S1 of t=0)
    if (XP > 0) {
        for (int kx = tid; kx < 460; kx += 448) {
            v4f xv;
            if (kx < 400)      xv = *(const v4f*)(prev + (size_t)kx * 64 + cb);
            else if (kx < 457) xv = *(const v4f*)(winb + (size_t)(kx - 400) * 64 + cb);
            else               xv = *(const v4f*)(xT + (size_t)(kx - 457) * 64 + cb);
            *(v4f*)&xcat_x[0][kx * 4] = xv;
        }
    } else {
        if (tid < 3)
            *(v4f*)&xcat_x[0][tid * 4] = *(const v4f*)(xT + (size_t)tid * 64 + cb);
    }

    for (int t = 0; t < Tx; ++t) {
        const int pl = t & 1;
        // ---- wait for h(t-1): wave 0 polls the single flag line, then release
        if (t > 0) {
            if (tid < 64) {
                int* fp = cnt_cg + (tid & 15);
                int fv = __hip_atomic_load(fp, __ATOMIC_RELAXED, __HIP_MEMORY_SCOPE_AGENT);
                while (!__all(fv >= t)) {
                    __builtin_amdgcn_s_sleep(1);
                    fv = __hip_atomic_load(fp, __ATOMIC_RELAXED, __HIP_MEMORY_SCOPE_AGENT);
                }
            }
            __syncthreads();   // release: h(t-1) globally visible
        }
        // ---- stage h(t-1)
        if (tid < 400) {
            v4f hv;
            if (t == 0) {
                hv.x = hinit[(size_t)(cb + 0) * 400 + tid];
                hv.y = hinit[(size_t)(cb + 1) * 400 + tid];
                hv.z = hinit[(size_t)(cb + 2) * 400 + tid];
                hv.w = hinit[(size_t)(cb + 3) * 400 + tid];
            } else {
                const float* hp0 = outL + (size_t)(t - 1) * 25600 + (size_t)tid * 64 + cb;
                asm volatile("global_load_dwordx4 %0, %1, off sc0 sc1"
                             : "=v"(hv) : "v"(hp0) : "memory");
                asm volatile("s_waitcnt vmcnt(0)" ::: "memory");
            }
            *(v4f*)&xcat_h[tid * 4] = hv;
            int d = tid - U0;
            if ((unsigned)d < 25u) *(v4f*)&hprev[t & 1][d * 4] = hv;
        }
        __syncthreads();   // S1: xcat_h + x-plane(pl) ready; red2 free

        // ---- dot
        if (q < 400) {
            v2f aR0 = {0, 0}, aR1 = {0, 0}, aZ0 = {0, 0}, aZ1 = {0, 0};
            v2f aHN0 = {0, 0}, aHN1 = {0, 0}, aXN0 = {0, 0}, aXN1 = {0, 0};
            const float* hb = &xcat_h[s * 100];
            #pragma unroll
            for (int p = 0; p < 13; ++p) {
                v2f a01 = *(const v2f*)(hb + 8 * p);
                v2f a23 = *(const v2f*)(hb + 8 * p + 2);
                v2f b01 = *(const v2f*)(hb + 8 * p + 4);
                v2f b23 = *(const v2f*)(hb + 8 * p + 6);
                v2f r_ = wr[p], z_ = wz[p], n_ = wn[p];
                pk_lo(aR0, r_, a01);  pk_lo(aR1, r_, a23);
                pk_hi(aR0, r_, b01);  pk_hi(aR1, r_, b23);
                pk_lo(aZ0, z_, a01);  pk_lo(aZ1, z_, a23);
                pk_hi(aZ0, z_, b01);  pk_hi(aZ1, z_, b23);
                pk_lo(aHN0, n_, a01); pk_lo(aHN1, n_, a23);
                pk_hi(aHN0, n_, b01); pk_hi(aHN1, n_, b23);
            }
            if (XP > 0) {
                const float* xb = &xcat_x[pl][s * 29 * 4];
                #pragma unroll
                for (int p = 0; p < XP; ++p) {
                    v2f a01 = *(const v2f*)(xb + 8 * p);
                    v2f a23 = *(const v2f*)(xb + 8 * p + 2);
                    v2f b01 = *(const v2f*)(xb + 8 * p + 4);
                    v2f b23 = *(const v2f*)(xb + 8 * p + 6);
                    v2f r_ = wr[13 + p], z_ = wz[13 + p], n_ = wn[13 + p];
                    pk_lo(aR0, r_, a01);  pk_lo(aR1, r_, a23);
                    pk_hi(aR0, r_, b01);  pk_hi(aR1, r_, b23);
                    pk_lo(aZ0, z_, a01);  pk_lo(aZ1, z_, a23);
                    pk_hi(aZ0, z_, b01);  pk_hi(aZ1, z_, b23);
                    pk_lo(aXN0, n_, a01); pk_lo(aXN1, n_, a23);
                    pk_hi(aXN0, n_, b01); pk_hi(aXN1, n_, b23);
                }
            }
            red2[0 * 400 + q] = aR0;  red2[1 * 400 + q] = aR1;
            red2[2 * 400 + q] = aZ0;  red2[3 * 400 + q] = aZ1;
            red2[4 * 400 + q] = aHN0; red2[5 * 400 + q] = aHN1;
            red2[6 * 400 + q] = aXN0; red2[7 * 400 + q] = aXN1;
        }
        __syncthreads();   // S2: red2 ready; xcat_h free for next step

        // ---- wave 0: reduce (2 outputs/lane) + activation + sc-store + signal
        if (tid < 64) {
            #pragma unroll
            for (int rep = 0; rep < 2; ++rep) {
                int o = tid + rep * 64;
                if (o < 100) {
                    int u = o >> 2, c = o & 3;
                    int half = c >> 1, e = c & 1;
                    const float* redf = (const float*)red2;
                    float R = 0, Z = 0, HN = 0, XN = 0;
                    #pragma unroll 4
                    for (int s2 = 0; s2 < 16; ++s2) {
                        int idx = s2 * 25 + u;
                        R  += redf[((0 + half) * 400 + idx) * 2 + e];
                        Z  += redf[((2 + half) * 400 + idx) * 2 + e];
                        HN += redf[((4 + half) * 400 + idx) * 2 + e];
                        XN += redf[((6 + half) * 400 + idx) * 2 + e];
                    }
                    R += biasLDS[u] + biasLDS[75 + u];
                    Z += biasLDS[25 + u] + biasLDS[100 + u];
                    XN += biasLDS[50 + u];
                    HN += biasLDS[125 + u];
                    if (XP == 0) {
                        #pragma unroll
                        for (int d = 0; d < 3; ++d) {
                            float xv = xcat_x[pl][d * 4 + c];
                            R  += wih0LDS[u * 9 + 0 + d] * xv;
                            Z  += wih0LDS[u * 9 + 3 + d] * xv;
                            XN += wih0LDS[u * 9 + 6 + d] * xv;
                        }
                    }
                    float r = sigf(R);
                    float z = sigf(Z);
                    float n = tanhf(XN + r * HN);
                    float hp = hprev[t & 1][u * 4 + c];
                    float hnew = (1.f - z) * n + z * hp;
                    __hip_atomic_store(outL + (size_t)t * 25600 + (size_t)(U0 + u) * 64 + cb + c,
                                       hnew, __ATOMIC_RELAXED, __HIP_MEMORY_SCOPE_AGENT);
                }
            }
            // single drain of this wave's sc-stores, then monotonic flag = t+1
            asm volatile("s_waitcnt vmcnt(0)" ::: "memory");
            if (tid == 0)
                __hip_atomic_store(cnt_cg + us, t + 1,
                                   __ATOMIC_RELAXED, __HIP_MEMORY_SCOPE_AGENT);
        } else if (t + 1 < Tx) {
            // ---- waves 1-6: prefetch x(t+1) into other plane
            const int p2 = (t + 1) & 1;
            if (XP > 0) {
                for (int kx = tid - 64; kx < 460; kx += 384) {
                    v4f xv;
                    if (kx < 400)      xv = *(const v4f*)(prev + (size_t)(t + 1) * 25600 + kx * 64 + cb);
                    else if (kx < 457) xv = *(const v4f*)(winb + (size_t)(t + 1) * 3648 + (kx - 400) * 64 + cb);
                    else               xv = *(const v4f*)(xT + (size_t)(t + 1) * 192 + (kx - 457) * 64 + cb);
                    *(v4f*)&xcat_x[p2][kx * 4] = xv;
                }
            } else {
                if (tid < 67) {
                    int d = tid - 64;
                    *(v4f*)&xcat_x[p2][d * 4] = *(const v4f*)(xT + (size_t)(t + 1) * 192 + d * 64 + cb);
                }
            }
        }
        // no third __syncthreads: next step's poll-release sync orders LDS.
    }
}

__global__ __launch_bounds__(256) void k_abk(const float* __restrict__ out0,
    const float* __restrict__ Wwin, const float* __restrict__ bwin,
    float* __restrict__ abk) {
    int t = blockIdx.x;
    int b = threadIdx.x & 63;
    int js = threadIdx.x >> 6;
    int j0 = js * 8;
    int nj = min(8, 30 - j0);
    float acc[8];
    for (int i = 0; i < nj; i++) acc[i] = bwin[j0 + i];
    const float* o = out0 + (size_t)t * 25600;
    for (int k = 0; k < Hx; k++) {
        float hv = o[k * 64 + b];
        for (int i = 0; i < nj; i++) acc[i] += Wwin[(j0 + i) * Hx + k] * hv;
    }
    for (int i = 0; i < nj; i++)
        abk[(size_t)t * 1920 + (j0 + i) * 64 + b] = expf(acc[i]);
}

__global__ void k_cumsum(float* __restrict__ abk) {
    int tid = blockIdx.x * blockDim.x + threadIdx.x;
    if (tid >= Kx * Bx) return;
    int b = tid & 63;
    int k = tid >> 6;
    float run = 0.f;
    size_t base = (size_t)(20 + k) * 64 + b;
    for (int t = 0; t < Tx; t++) {
        size_t i = (size_t)t * 1920 + base;
        run += abk[i];
        abk[i] = run;
    }
}

__global__ __launch_bounds__(256) void k_window(const float* __restrict__ abk,
    const float* __restrict__ ohT, float* __restrict__ win) {
    int t = blockIdx.x;
    int b = threadIdx.x & 63;
    int sub = threadIdx.x >> 6;
    __shared__ float phi[Ux][64];

    float al[Kx], be[Kx], kc[Kx];
    const float* ab = abk + (size_t)t * 1920;
    #pragma unroll
    for (int k = 0; k < Kx; k++) {
        al[k] = ab[k * 64 + b];
        be[k] = ab[(10 + k) * 64 + b];
        kc[k] = ab[(20 + k) * 64 + b];
    }
    for (int u = sub * 20; u < sub * 20 + 20; u++) {
        float ssum = 0.f;
        float uf = (float)u;
        #pragma unroll
        for (int k = 0; k < Kx; k++) {
            float d = kc[k] - uf;
            ssum += al[k] * __expf(-be[k] * d * d);
        }
        phi[u][b] = ssum;
    }
    __syncthreads();

    int v0 = sub * 15;
    int nv = min(15, Vx - v0);
    float acc[15];
    for (int i = 0; i < nv; i++) acc[i] = 0.f;
    for (int u = 0; u < Ux; u++) {
        float pv = phi[u][b];
        const float* oh = ohT + (size_t)(u * Vx) * 64;
        for (int i = 0; i < nv; i++) acc[i] += pv * oh[(v0 + i) * 64 + b];
    }
    for (int i = 0; i < nv; i++)
        win[(size_t)t * 3648 + (v0 + i) * 64 + b] = acc[i];
}

__global__ __launch_bounds__(256) void k_mdn(const float* __restrict__ out2,
    const float* __restrict__ Wm, const float* __restrict__ bm,
    float* __restrict__ out) {
    int t = blockIdx.x;
    int b = threadIdx.x & 63;
    int js = threadIdx.x >> 6;
    int j0 = js * 31;
    int nj = min(31, 121 - j0);
    float acc[31];
    for (int i = 0; i < nj; i++) acc[i] = bm[j0 + i];
    const float* o = out2 + (size_t)t * 25600;
    for (int k = 0; k < Hx; k += 4) {
        float i0 = o[k * 64 + b];
        float i1 = o[(k + 1) * 64 + b];
        float i2 = o[(k + 2) * 64 + b];
        float i3 = o[(k + 3) * 64 + b];
        for (int i = 0; i < nj; i++) {
            const float* wp = Wm + (size_t)(j0 + i) * Hx + k;
            float4 qv = *(const float4*)wp;
            acc[i] += qv.x * i0 + qv.y * i1 + qv.z * i2 + qv.w * i3;
        }
    }
    size_t rb = ((size_t)b * Tx + t) * 121;
    for (int i = 0; i < nj; i++) {
        int j = j0 + i;
        float v = acc[i];
        if (j >= 100 && j < 120) v = tanhf(v);
        out[rb + j] = v;
    }
}

extern "C" void kernel_launch(void* const* d_in, const int* in_sizes, int n_in,
                              void* d_out, int out_size, void* d_ws, size_t ws_size,
                              hipStream_t stream) {
    const float* x    = (const float*)d_in[0];
    const float* oneh = (const float*)d_in[1];
    const float* h0i  = (const float*)d_in[2];
    const float* h1i  = (const float*)d_in[3];
    const float* h2i  = (const float*)d_in[4];
    const float* Wih0 = (const float*)d_in[5];
    const float* Whh0 = (const float*)d_in[6];
    const float* bih0 = (const float*)d_in[7];
    const float* bhh0 = (const float*)d_in[8];
    const float* Wih1 = (const float*)d_in[9];
    const float* Whh1 = (const float*)d_in[10];
    const float* bih1 = (const float*)d_in[11];
    const float* bhh1 = (const float*)d_in[12];
    const float* Wwin = (const float*)d_in[13];
    const float* bwin = (const float*)d_in[14];
    const float* Wmdn = (const float*)d_in[15];
    const float* bmdn = (const float*)d_in[16];

    float* ws    = (float*)d_ws;
    float* out0  = ws;                    // 20,480,000
    float* out12 = ws + 20480000;         // 20,480,000
    float* winb  = ws + 40960000;         //  2,918,400
    float* abk   = ws + 43878400;         //  1,536,000
    float* xT    = ws + 45414400;         //    153,600
    float* ohT   = ws + 45568000;         //    291,840
    float* Wp0   = ws + 45859840;         //    499,200
    float* Wp12  = ws + 46359040;         //  1,075,200
    int*   cnt   = (int*)(ws + 47434240); //      1,536 ints

    hipLaunchKernelGGL(k_zero, dim3(6), dim3(256), 0, stream, cnt);
    hipLaunchKernelGGL(k_transpose_x, dim3((Tx * INx * Bx + 255) / 256), dim3(256), 0, stream, x, xT);
    hipLaunchKernelGGL(k_transpose_oh, dim3((Ux * Vx * Bx + 255) / 256), dim3(256), 0, stream, oneh, ohT);
    hipLaunchKernelGGL(k_packW, dim3((16 * 3 * 13 * 400 + 255) / 256), dim3(256), 0, stream,
                       Whh0, Wih0, Wp0, 13, 3);
    hipLaunchKernelGGL(k_packW, dim3((16 * 3 * 28 * 400 + 255) / 256), dim3(256), 0, stream,
                       Whh1, Wih1, Wp12, 28, 460);

    hipLaunchKernelGGL((k_rec<0>), dim3(256), dim3(448), 0, stream,
                       Wp0, (const float*)nullptr, (const float*)nullptr, xT,
                       h0i, Wih0, bih0, bhh0, out0, cnt + 0 * 512);

    hipLaunchKernelGGL(k_abk, dim3(Tx), dim3(256), 0, stream, out0, Wwin, bwin, abk);
    hipLaunchKernelGGL(k_cumsum, dim3(10), dim3(64), 0, stream, abk);
    hipLaunchKernelGGL(k_window, dim3(Tx), dim3(256), 0, stream, abk, ohT, winb);

    hipLaunchKernelGGL((k_rec<15>), dim3(256), dim3(448), 0, stream,
                       Wp12, out0, winb, xT, h1i, (const float*)nullptr,
                       bih1, bhh1, out12, cnt + 1 * 512);
    hipLaunchKernelGGL((k_rec<15>), dim3(256), dim3(448), 0, stream,
                       Wp12, out12, winb, xT, h2i, (const float*)nullptr,
                       bih1, bhh1, out0, cnt + 2 * 512);

    hipLaunchKernelGGL(k_mdn, dim3(Tx), dim3(256), 0, stream, out0, Wmdn, bmdn, (float*)d_out);
}